// Round 19
// baseline (234.570 us; speedup 1.0000x reference)
//
#include <hip/hip_runtime.h>

// FP contraction OFF file-wide: margin/candidate arithmetic must be plain
// rounded ops (hipcc defaults contract=fast; __f*_rn are NOT barriers).
#pragma clang fp contract(off)

typedef __attribute__((ext_vector_type(8))) short short8;
typedef __attribute__((ext_vector_type(4))) float floatx4;

#define NROWS 262144
#define CAP   32768

static __device__ __forceinline__ unsigned short f32_to_bf16_rne(float f) {
    unsigned int u = __float_as_uint(f);
    u += 0x7fffu + ((u >> 16) & 1u);
    return (unsigned short)(u >> 16);
}
static __device__ __forceinline__ float bf16f(float v) {
    return __uint_as_float(((unsigned int)f32_to_bf16_rne(v)) << 16);
}

static __device__ __forceinline__ void pack8_split(float4 v0, float4 v1,
                                                   short8& hi8, short8& lo8) {
    union { short8 s; unsigned short u[8]; } H, L;
    float f[8] = {v0.x, v0.y, v0.z, v0.w, v1.x, v1.y, v1.z, v1.w};
    #pragma unroll
    for (int i = 0; i < 8; ++i) {
        unsigned short h = f32_to_bf16_rne(f[i]);
        float fh = __uint_as_float((unsigned int)h << 16);
        H.u[i] = h;
        L.u[i] = f32_to_bf16_rne(f[i] - fh);
    }
    hi8 = H.s; lo8 = L.s;
}

// async global->LDS, 16B per lane (dest = wave-uniform base + lane*16, linear)
#define GLOAD_LDS(g, l) __builtin_amdgcn_global_load_lds(                    \
        (const __attribute__((address_space(1))) void*)(g),                  \
        (__attribute__((address_space(3))) void*)(l), 16, 0, 0)

// cross-lane helpers within a 16-lane group:
// xor1 = quad_perm 0xB1, xor2 = quad_perm 0x4E, xor4 = ds_swizzle 0x101F,
// xor8 = dpp row_ror:8 (0x128).  [certified by R13's bit-identical sort]
#define DPPF(V, C) __uint_as_float(__builtin_amdgcn_mov_dpp(                 \
                       __float_as_uint(V), (C), 0xF, 0xF, true))
#define SWZF(V)    __uint_as_float(__builtin_amdgcn_ds_swizzle(              \
                       __float_as_uint(V), 0x101F))

// in-lane compare-exchange substep, compile-time direction
#define SWAP_IN(D, UPC)                                                   \
    _Pragma("unroll") for (int j = 0; j < 16; ++j) if (!(j & (D))) {      \
        const int j2 = j | (D);                                           \
        const bool up_ = (UPC);                                           \
        float aa_ = ys[j], bb_ = ys[j2];                                  \
        float mn_ = fminf(aa_, bb_), mx_ = fmaxf(aa_, bb_);               \
        ys[j] = up_ ? mn_ : mx_; ys[j2] = up_ ? mx_ : mn_; }

// ---- prep: split W into bf16 hi/lo; layout contiguous per kb-slice:
// off_ushort = kb*16384 + n*1024 + part*512 + lane*8 + j
__global__ void prep_kernel(const float* __restrict__ W,
                            unsigned short* __restrict__ Wp,
                            unsigned int* __restrict__ counter) {
    if (blockIdx.x == 0 && threadIdx.x == 0) *counter = 0;
    const int row = blockIdx.x;
    const int col = threadIdx.x;
    const float w = W[row * 256 + col];
    const unsigned short h = f32_to_bf16_rne(w);
    const float fh = __uint_as_float(((unsigned int)h) << 16);
    const unsigned short l = f32_to_bf16_rne(w - fh);
    const int n = row >> 4, lo16 = row & 15;
    const int kb = col >> 5, hi4 = (col >> 3) & 3, j = col & 7;
    const int lane = hi4 * 16 + lo16;
    const int base = kb * 16384 + n * 1024 + lane * 8 + j;
    Wp[base] = h;            // part 0 (hi)
    Wp[base + 512] = l;      // part 1 (lo)
}

// ---- pass 1: wave-owns-16-rows fused GEMM (async dbuf LDS B) + tail epilogue
__global__ __launch_bounds__(256, 2) void pass1_fused(
    const float* __restrict__ x, const unsigned short* __restrict__ Wp,
    float* __restrict__ out, unsigned int* __restrict__ counter,
    unsigned int* __restrict__ list)
{
    __shared__ __align__(16) unsigned short sW[2][16384];   // 64 KB dbuf
    const int tid  = threadIdx.x;
    const int wave = tid >> 6;
    const int lane = tid & 63;
    const int lo   = lane & 15;
    const int hi   = lane >> 4;
    const size_t wrow0 = (size_t)blockIdx.x * 64 + wave * 16;
    const unsigned long long gmask = 0xFFFFull << (hi * 16);

    floatx4 acc[16];
    #pragma unroll
    for (int n = 0; n < 16; ++n) acc[n] = (floatx4){0.f, 0.f, 0.f, 0.f};

    const float* pAa = x + (wrow0 + (size_t)lo) * 256 + hi * 8;
    float4 va0 = ((const float4*)pAa)[0];
    float4 va1 = ((const float4*)pAa)[1];

    // prologue: stage kb=0 into buf 0 (each wave stages its 8 KB)
    #pragma unroll
    for (int i = 0; i < 8; ++i)
        GLOAD_LDS(Wp + (wave * 8 + i) * 512 + lane * 8,
                  &sW[0][(wave * 8 + i) * 512]);
    asm volatile("s_waitcnt vmcnt(0)" ::: "memory");
    __syncthreads();

    #pragma unroll 1
    for (int kb = 0; kb < 8; ++kb) {
        const int cur = kb & 1;
        // async stage of next slice into the other buffer (hidden under compute)
        if (kb < 7) {
            #pragma unroll
            for (int i = 0; i < 8; ++i)
                GLOAD_LDS(Wp + (kb + 1) * 16384 + (wave * 8 + i) * 512 + lane * 8,
                          &sW[cur ^ 1][(wave * 8 + i) * 512]);
        }
        // A prefetch for next kb (HBM latency hides under compute too)
        float4 na0 = va0, na1 = va1;
        if (kb < 7) {
            const float4* pn = (const float4*)(pAa + (kb + 1) * 32);
            na0 = pn[0]; na1 = pn[1];
        }

        short8 a0, a1;
        pack8_split(va0, va1, a0, a1);
        const unsigned short* sws = &sW[cur][0];
        #pragma unroll
        for (int n = 0; n < 16; ++n) {
            const short8 bh = *(const short8*)(sws + n * 1024 + lane * 8);
            const short8 bl = *(const short8*)(sws + n * 1024 + 512 + lane * 8);
            acc[n] = __builtin_amdgcn_mfma_f32_16x16x32_bf16(a1, bh, acc[n], 0, 0, 0);
            acc[n] = __builtin_amdgcn_mfma_f32_16x16x32_bf16(a0, bl, acc[n], 0, 0, 0);
            acc[n] = __builtin_amdgcn_mfma_f32_16x16x32_bf16(a0, bh, acc[n], 0, 0, 0);
        }
        va0 = na0; va1 = na1;

        // drain my async stage + sync all waves (one barrier per kb)
        asm volatile("s_waitcnt vmcnt(0)" ::: "memory");
        __syncthreads();
    }

    // Epilogue: fully unrolled rr -> acc[n][rr] direct register reads
    #pragma unroll
    for (int rr = 0; rr < 4; ++rr) {
        const size_t grow = wrow0 + hi * 4 + rr;

        float ys[16];
        #pragma unroll
        for (int n = 0; n < 16; ++n) ys[n] = acc[n][rr];   // z values

        float s = 0.f;
        #pragma unroll
        for (int j = 0; j < 16; ++j) s += ys[j];

        // in-lane ascending bitonic-16 (compile-time directions only)
        SWAP_IN(1, (j & 2) == 0)
        SWAP_IN(2, (j & 4) == 0) SWAP_IN(1, (j & 4) == 0)
        SWAP_IN(4, (j & 8) == 0) SWAP_IN(2, (j & 8) == 0) SWAP_IN(1, (j & 8) == 0)
        SWAP_IN(8, true) SWAP_IN(4, true) SWAP_IN(2, true) SWAP_IN(1, true)

        // group-wide sum and max
        s += DPPF(s, 0xB1); s += DPPF(s, 0x4E); s += SWZF(s); s += DPPF(s, 0x128);
        float zx = ys[15];
        zx = fmaxf(zx, DPPF(zx, 0xB1)); zx = fmaxf(zx, DPPF(zx, 0x4E));
        zx = fmaxf(zx, SWZF(zx));        zx = fmaxf(zx, DPPF(zx, 0x128));

        // pop-min loop: strip bottom values until running sum exceeds 1
        float R = s;
        float Rp = 0.0f;
        int ii = 0;
        #pragma unroll 1
        while (R <= 1.0f && ii < 48) {
            float m = ys[0];
            m = fminf(m, DPPF(m, 0xB1));
            m = fminf(m, DPPF(m, 0x4E));
            m = fminf(m, SWZF(m));
            m = fminf(m, DPPF(m, 0x128));
            unsigned long long bal = __ballot(ys[0] == m) & gmask;
            int below = __builtin_amdgcn_mbcnt_hi(
                (unsigned int)(bal >> 32),
                __builtin_amdgcn_mbcnt_lo((unsigned int)bal, 0));
            const bool first = (ys[0] == m) && (below == 0);
            #pragma unroll
            for (int q = 0; q < 15; ++q) ys[q] = first ? ys[q + 1] : ys[q];
            ys[15] = first ? 3.0e38f : ys[15];
            Rp = R;
            R = R - m;
            ++ii;
        }
        const bool capped = (R <= 1.0f);

        float bn = ys[0];
        bn = fminf(bn, DPPF(bn, 0xB1));
        bn = fminf(bn, DPPF(bn, 0x4E));
        bn = fminf(bn, SWZF(bn));
        bn = fminf(bn, DPPF(bn, 0x128));

        const int   Kv = 256 - ii;
        const float Kf = (float)Kv;
        const float tau = ((1.0f + Kf * bn) - R) / Kf;   // cand[K-1], plain rn

        const float tailmg = (ii == 0) ? (R - 1.0f) : fminf(R - 1.0f, 1.0f - Rp);
        const bool flagc = (tailmg < 2.0e-3f) || capped || (zx < 1.02f);
        if (lo == 0 && flagc) {
            unsigned int idx = atomicAdd(counter, 1u);
            if (idx < CAP) list[idx] = (unsigned int)grow;
        }

        float* orow = out + grow * 256;
        #pragma unroll
        for (int n = 0; n < 16; ++n)
            orow[n * 16 + lo] = fmaxf(acc[n][rr] - tau, 0.f);
    }
}

// ---- pass 2: f64 tail-selection redo + reported-absmax feedback ----
#define CE2(a, b) { double l_ = fmin(zd[a], zd[b]), h_ = fmax(zd[a], zd[b]); \
                    zd[a] = l_; zd[b] = h_; }

__global__ __launch_bounds__(256) void exact_redo_f64(
    const float* __restrict__ x, const float* __restrict__ W,
    const unsigned int* __restrict__ counter,
    const unsigned int* __restrict__ list, float* __restrict__ out)
{
    __shared__ __align__(16) float xsh[256];
    __shared__ double zsh[256];
    __shared__ double par[8];   // 0:tau_m 1:tau_p 2:tau_q 3:mg 4:K 5:tau_final
    __shared__ float red[4][2];
    const int tid = threadIdx.x;
    unsigned int cnt_rows = *counter;
    if (cnt_rows > CAP) cnt_rows = CAP;

    for (unsigned int i = blockIdx.x; i < cnt_rows; i += gridDim.x) {
        const size_t r = list[i];
        xsh[tid] = x[r * 256 + tid];
        __syncthreads();

        double acc = 0.0;
        const float4* wr4 = (const float4*)(W + (size_t)tid * 256);
        #pragma unroll 4
        for (int d4 = 0; d4 < 64; ++d4) {
            float4 w = wr4[d4];
            float4 xx = *(const float4*)&xsh[d4 * 4];
            acc = fma((double)w.x, (double)xx.x, acc);
            acc = fma((double)w.y, (double)xx.y, acc);
            acc = fma((double)w.z, (double)xx.z, acc);
            acc = fma((double)w.w, (double)xx.w, acc);
        }
        zsh[tid] = acc;
        __syncthreads();

        if (tid < 64) {
            double zd[4];
            #pragma unroll
            for (int q = 0; q < 4; ++q) zd[q] = zsh[tid * 4 + q];
            double S = ((zd[0] + zd[1]) + (zd[2] + zd[3]));
            #pragma unroll
            for (int m = 1; m < 64; m <<= 1) S += __shfl_xor(S, m, 64);
            CE2(0, 1) CE2(2, 3) CE2(0, 2) CE2(1, 3) CE2(1, 2)

            double R = S, Rp = 0.0, mlast = 0.0;
            int ii = 0;
            #pragma unroll 1
            while (R <= 1.0 && ii < 64) {
                double m = zd[0];
                #pragma unroll
                for (int mm = 1; mm < 64; mm <<= 1) m = fmin(m, __shfl_xor(m, mm, 64));
                unsigned long long bal = __ballot(zd[0] == m);
                int below = __builtin_amdgcn_mbcnt_hi(
                    (unsigned int)(bal >> 32),
                    __builtin_amdgcn_mbcnt_lo((unsigned int)bal, 0));
                const bool first = (zd[0] == m) && (below == 0);
                zd[0] = first ? zd[1] : zd[0];
                zd[1] = first ? zd[2] : zd[1];
                zd[2] = first ? zd[3] : zd[2];
                zd[3] = first ? 1.0e300 : zd[3];
                Rp = R; mlast = m;
                R = R - m;
                ++ii;
            }

            double b1 = zd[0];
            #pragma unroll
            for (int mm = 1; mm < 64; mm <<= 1) b1 = fmin(b1, __shfl_xor(b1, mm, 64));
            {
                unsigned long long bal = __ballot(zd[0] == b1);
                int below = __builtin_amdgcn_mbcnt_hi(
                    (unsigned int)(bal >> 32),
                    __builtin_amdgcn_mbcnt_lo((unsigned int)bal, 0));
                const bool first = (zd[0] == b1) && (below == 0);
                zd[0] = first ? zd[1] : zd[0];
                zd[1] = first ? zd[2] : zd[1];
                zd[2] = first ? zd[3] : zd[2];
                zd[3] = first ? 1.0e300 : zd[3];
            }
            double b2 = zd[0];
            #pragma unroll
            for (int mm = 1; mm < 64; mm <<= 1) b2 = fmin(b2, __shfl_xor(b2, mm, 64));

            const int K = 256 - ii;
            const double Kd = (double)K;
            const double tau_m = ((1.0 + Kd * b1) - R) / Kd;
            double tau_p = tau_m, tau_q = tau_m;
            if (ii >= 1)
                tau_p = ((1.0 + (Kd + 1.0) * mlast) - Rp) / (Kd + 1.0);
            if (K >= 2)
                tau_q = ((1.0 + (Kd - 1.0) * b2) - (R - b1)) / (Kd - 1.0);
            double mg = fabs(R - 1.0);
            if (ii >= 1) mg = fmin(mg, fabs(Rp - 1.0));

            if (tid == 0) {
                par[0] = tau_m; par[1] = tau_p; par[2] = tau_q;
                par[3] = mg;    par[4] = (double)K;
            }
        }
        __syncthreads();

        const double tau_m = par[0], tau_p = par[1], tau_q = par[2];
        const int K = (int)par[4];
        const bool hasp = (K <= 255);
        const bool hasq = (K >= 2);

        const float om = bf16f((float)fmax(zsh[tid] - tau_m, 0.0));
        const float op = bf16f((float)fmax(zsh[tid] - tau_p, 0.0));
        const float oq = bf16f((float)fmax(zsh[tid] - tau_q, 0.0));
        float dp = fabsf(op - om);
        float dq = fabsf(oq - om);
        #pragma unroll
        for (int m = 1; m < 64; m <<= 1) {
            dp = fmaxf(dp, __shfl_xor(dp, m, 64));
            dq = fmaxf(dq, __shfl_xor(dq, m, 64));
        }
        if ((tid & 63) == 0) { red[tid >> 6][0] = dp; red[tid >> 6][1] = dq; }
        __syncthreads();

        if (tid == 0) {
            const float Ep = fmaxf(fmaxf(red[0][0], red[1][0]),
                                   fmaxf(red[2][0], red[3][0]));
            const float Eq = fmaxf(fmaxf(red[0][1], red[1][1]),
                                   fmaxf(red[2][1], red[3][1]));
            double tf = tau_m;
            if (par[3] < 1.2e-4) {
                const float EL[1] = {0.46875f};
                #pragma unroll
                for (int t = 0; t < 1; ++t) {
                    if (hasp && Ep == EL[t]) { tf = tau_p; break; }
                    if (hasq && Eq == EL[t]) { tf = tau_q; break; }
                }
            }
            par[5] = tf;
        }
        __syncthreads();

        out[r * 256 + tid] = (float)fmax(zsh[tid] - par[5], 0.0);
        __syncthreads();
    }
}

extern "C" void kernel_launch(void* const* d_in, const int* in_sizes, int n_in,
                              void* d_out, int out_size, void* d_ws, size_t ws_size,
                              hipStream_t stream) {
    const float* x = (const float*)d_in[0];
    const float* W = (const float*)d_in[1];
    float* out = (float*)d_out;

    unsigned short* Wp = (unsigned short*)d_ws;
    unsigned int* counter = (unsigned int*)((char*)d_ws + 262144);
    unsigned int* list    = (unsigned int*)((char*)d_ws + 262144 + 64);

    hipLaunchKernelGGL(prep_kernel, dim3(256), dim3(256), 0, stream, W, Wp, counter);

    const int N = in_sizes[0] / 256;   // 262144
    hipLaunchKernelGGL(pass1_fused, dim3(N / 64), dim3(256), 0, stream,
                       x, Wp, out, counter, list);
    hipLaunchKernelGGL(exact_redo_f64, dim3(8192), dim3(256), 0, stream,
                       x, W, counter, list, out);
}

// Round 20
// 199.279 us; speedup vs baseline: 1.1771x; 1.1771x over previous
//
#include <hip/hip_runtime.h>

// FP contraction OFF file-wide: margin/candidate arithmetic must be plain
// rounded ops (hipcc defaults contract=fast; __f*_rn are NOT barriers).
#pragma clang fp contract(off)

typedef __attribute__((ext_vector_type(8))) short short8;
typedef __attribute__((ext_vector_type(4))) float floatx4;

#define NROWS 262144
#define CAP   32768

static __device__ __forceinline__ unsigned short f32_to_bf16_rne(float f) {
    unsigned int u = __float_as_uint(f);
    u += 0x7fffu + ((u >> 16) & 1u);
    return (unsigned short)(u >> 16);
}
static __device__ __forceinline__ float bf16f(float v) {
    return __uint_as_float(((unsigned int)f32_to_bf16_rne(v)) << 16);
}

static __device__ __forceinline__ void pack8_split(float4 v0, float4 v1,
                                                   short8& hi8, short8& lo8) {
    union { short8 s; unsigned short u[8]; } H, L;
    float f[8] = {v0.x, v0.y, v0.z, v0.w, v1.x, v1.y, v1.z, v1.w};
    #pragma unroll
    for (int i = 0; i < 8; ++i) {
        unsigned short h = f32_to_bf16_rne(f[i]);
        float fh = __uint_as_float((unsigned int)h << 16);
        H.u[i] = h;
        L.u[i] = f32_to_bf16_rne(f[i] - fh);
    }
    hi8 = H.s; lo8 = L.s;
}

// async global->LDS, 16B per lane (dest = wave-uniform base + lane*16, linear)
#define GLOAD_LDS(g, l) __builtin_amdgcn_global_load_lds(                    \
        (const __attribute__((address_space(1))) void*)(g),                  \
        (__attribute__((address_space(3))) void*)(l), 16, 0, 0)

// cross-lane helpers within a 16-lane group:
// xor1 = quad_perm 0xB1, xor2 = quad_perm 0x4E, xor4 = ds_swizzle 0x101F,
// xor8 = dpp row_ror:8 (0x128).  [certified by R13's bit-identical sort]
#define DPPF(V, C) __uint_as_float(__builtin_amdgcn_mov_dpp(                 \
                       __float_as_uint(V), (C), 0xF, 0xF, true))
#define SWZF(V)    __uint_as_float(__builtin_amdgcn_ds_swizzle(              \
                       __float_as_uint(V), 0x101F))

// in-lane compare-exchange substep, compile-time direction
#define SWAP_IN(D, UPC)                                                   \
    _Pragma("unroll") for (int j = 0; j < 16; ++j) if (!(j & (D))) {      \
        const int j2 = j | (D);                                           \
        const bool up_ = (UPC);                                           \
        float aa_ = ys[j], bb_ = ys[j2];                                  \
        float mn_ = fminf(aa_, bb_), mx_ = fmaxf(aa_, bb_);               \
        ys[j] = up_ ? mn_ : mx_; ys[j2] = up_ ? mx_ : mn_; }

// ---- prep: split W into bf16 hi/lo; layout contiguous per kb-slice:
// off_ushort = kb*16384 + n*1024 + part*512 + lane*8 + j
// (half-slice = n 0..7 or 8..15 = 8192 ushorts = 16 KB, contiguous)
__global__ void prep_kernel(const float* __restrict__ W,
                            unsigned short* __restrict__ Wp,
                            unsigned int* __restrict__ counter) {
    if (blockIdx.x == 0 && threadIdx.x == 0) *counter = 0;
    const int row = blockIdx.x;
    const int col = threadIdx.x;
    const float w = W[row * 256 + col];
    const unsigned short h = f32_to_bf16_rne(w);
    const float fh = __uint_as_float(((unsigned int)h) << 16);
    const unsigned short l = f32_to_bf16_rne(w - fh);
    const int n = row >> 4, lo16 = row & 15;
    const int kb = col >> 5, hi4 = (col >> 3) & 3, j = col & 7;
    const int lane = hi4 * 16 + lo16;
    const int base = kb * 16384 + n * 1024 + lane * 8 + j;
    Wp[base] = h;            // part 0 (hi)
    Wp[base + 512] = l;      // part 1 (lo)
}

// stage one 16 KB half-slice (step s) into buffer b: 4 GLOAD_LDS per wave
#define STAGE_HALF(s, b)                                                     \
    _Pragma("unroll")                                                        \
    for (int i_ = 0; i_ < 4; ++i_)                                           \
        GLOAD_LDS(Wp + (size_t)(s) * 8192 + (wave * 4 + i_) * 512 + lane * 8,\
                  &sW[(b)][(wave * 4 + i_) * 512]);

// compute 8 n-values [N0..N0+7] from buffer b (N0 compile-time!)
#define COMPUTE_HALF(N0, b)                                                  \
    _Pragma("unroll")                                                        \
    for (int nl = 0; nl < 8; ++nl) {                                         \
        const short8 bh = *(const short8*)(&sW[(b)][nl * 1024 + lane * 8]);  \
        const short8 bl = *(const short8*)(&sW[(b)][nl * 1024 + 512 + lane * 8]); \
        acc[(N0) + nl] = __builtin_amdgcn_mfma_f32_16x16x32_bf16(a1, bh, acc[(N0) + nl], 0, 0, 0); \
        acc[(N0) + nl] = __builtin_amdgcn_mfma_f32_16x16x32_bf16(a0, bl, acc[(N0) + nl], 0, 0, 0); \
        acc[(N0) + nl] = __builtin_amdgcn_mfma_f32_16x16x32_bf16(a0, bh, acc[(N0) + nl], 0, 0, 0); \
    }

// ---- pass 1: wave-owns-16-rows fused GEMM (async half-slice dbuf) ----
__global__ __launch_bounds__(256, 4) void pass1_fused(
    const float* __restrict__ x, const unsigned short* __restrict__ Wp,
    float* __restrict__ out, unsigned int* __restrict__ counter,
    unsigned int* __restrict__ list)
{
    __shared__ __align__(16) unsigned short sW[2][8192];   // 32 KB dbuf
    const int tid  = threadIdx.x;
    const int wave = tid >> 6;
    const int lane = tid & 63;
    const int lo   = lane & 15;
    const int hi   = lane >> 4;
    const size_t wrow0 = (size_t)blockIdx.x * 64 + wave * 16;
    const unsigned long long gmask = 0xFFFFull << (hi * 16);

    floatx4 acc[16];
    #pragma unroll
    for (int n = 0; n < 16; ++n) acc[n] = (floatx4){0.f, 0.f, 0.f, 0.f};

    const float* pAa = x + (wrow0 + (size_t)lo) * 256 + hi * 8;
    float4 va0 = ((const float4*)pAa)[0];
    float4 va1 = ((const float4*)pAa)[1];

    // prologue: stage step 0 (kb=0, n=0..7) into buf 0
    STAGE_HALF(0, 0)
    asm volatile("s_waitcnt vmcnt(0)" ::: "memory");
    __syncthreads();

    #pragma unroll 1
    for (int kb = 0; kb < 8; ++kb) {
        // ---- step 2kb (hf=0): stage step 2kb+1 -> buf1; compute n=0..7 from buf0
        STAGE_HALF(2 * kb + 1, 1)
        // A prefetch for next kb (latency hides under both half-steps)
        float4 na0 = va0, na1 = va1;
        if (kb < 7) {
            const float4* pn = (const float4*)(pAa + (kb + 1) * 32);
            na0 = pn[0]; na1 = pn[1];
        }
        short8 a0, a1;
        pack8_split(va0, va1, a0, a1);

        COMPUTE_HALF(0, 0)
        asm volatile("s_waitcnt vmcnt(0)" ::: "memory");
        __syncthreads();

        // ---- step 2kb+1 (hf=1): stage step 2kb+2 -> buf0; compute n=8..15 from buf1
        if (kb < 7) { STAGE_HALF(2 * kb + 2, 0) }
        COMPUTE_HALF(8, 1)
        asm volatile("s_waitcnt vmcnt(0)" ::: "memory");
        __syncthreads();

        va0 = na0; va1 = na1;
    }

    // Epilogue: fully unrolled rr -> acc[n][rr] direct register reads
    #pragma unroll
    for (int rr = 0; rr < 4; ++rr) {
        const size_t grow = wrow0 + hi * 4 + rr;

        float ys[16];
        #pragma unroll
        for (int n = 0; n < 16; ++n) ys[n] = acc[n][rr];   // z values

        float s = 0.f;
        #pragma unroll
        for (int j = 0; j < 16; ++j) s += ys[j];

        // in-lane ascending bitonic-16 (compile-time directions only)
        SWAP_IN(1, (j & 2) == 0)
        SWAP_IN(2, (j & 4) == 0) SWAP_IN(1, (j & 4) == 0)
        SWAP_IN(4, (j & 8) == 0) SWAP_IN(2, (j & 8) == 0) SWAP_IN(1, (j & 8) == 0)
        SWAP_IN(8, true) SWAP_IN(4, true) SWAP_IN(2, true) SWAP_IN(1, true)

        // group-wide sum and max
        s += DPPF(s, 0xB1); s += DPPF(s, 0x4E); s += SWZF(s); s += DPPF(s, 0x128);
        float zx = ys[15];
        zx = fmaxf(zx, DPPF(zx, 0xB1)); zx = fmaxf(zx, DPPF(zx, 0x4E));
        zx = fmaxf(zx, SWZF(zx));        zx = fmaxf(zx, DPPF(zx, 0x128));

        // pop-min loop: strip bottom values until running sum exceeds 1
        float R = s;
        float Rp = 0.0f;
        int ii = 0;
        #pragma unroll 1
        while (R <= 1.0f && ii < 48) {
            float m = ys[0];
            m = fminf(m, DPPF(m, 0xB1));
            m = fminf(m, DPPF(m, 0x4E));
            m = fminf(m, SWZF(m));
            m = fminf(m, DPPF(m, 0x128));
            unsigned long long bal = __ballot(ys[0] == m) & gmask;
            int below = __builtin_amdgcn_mbcnt_hi(
                (unsigned int)(bal >> 32),
                __builtin_amdgcn_mbcnt_lo((unsigned int)bal, 0));
            const bool first = (ys[0] == m) && (below == 0);
            #pragma unroll
            for (int q = 0; q < 15; ++q) ys[q] = first ? ys[q + 1] : ys[q];
            ys[15] = first ? 3.0e38f : ys[15];
            Rp = R;
            R = R - m;
            ++ii;
        }
        const bool capped = (R <= 1.0f);

        float bn = ys[0];
        bn = fminf(bn, DPPF(bn, 0xB1));
        bn = fminf(bn, DPPF(bn, 0x4E));
        bn = fminf(bn, SWZF(bn));
        bn = fminf(bn, DPPF(bn, 0x128));

        const int   Kv = 256 - ii;
        const float Kf = (float)Kv;
        const float tau = ((1.0f + Kf * bn) - R) / Kf;   // cand[K-1], plain rn

        const float tailmg = (ii == 0) ? (R - 1.0f) : fminf(R - 1.0f, 1.0f - Rp);
        const bool flagc = (tailmg < 2.0e-3f) || capped || (zx < 1.02f);
        if (lo == 0 && flagc) {
            unsigned int idx = atomicAdd(counter, 1u);
            if (idx < CAP) list[idx] = (unsigned int)grow;
        }

        float* orow = out + grow * 256;
        #pragma unroll
        for (int n = 0; n < 16; ++n)
            orow[n * 16 + lo] = fmaxf(acc[n][rr] - tau, 0.f);
    }
}

// ---- pass 2: f64 tail-selection redo + reported-absmax feedback ----
#define CE2(a, b) { double l_ = fmin(zd[a], zd[b]), h_ = fmax(zd[a], zd[b]); \
                    zd[a] = l_; zd[b] = h_; }

__global__ __launch_bounds__(256) void exact_redo_f64(
    const float* __restrict__ x, const float* __restrict__ W,
    const unsigned int* __restrict__ counter,
    const unsigned int* __restrict__ list, float* __restrict__ out)
{
    __shared__ __align__(16) float xsh[256];
    __shared__ double zsh[256];
    __shared__ double par[8];   // 0:tau_m 1:tau_p 2:tau_q 3:mg 4:K 5:tau_final
    __shared__ float red[4][2];
    const int tid = threadIdx.x;
    unsigned int cnt_rows = *counter;
    if (cnt_rows > CAP) cnt_rows = CAP;

    for (unsigned int i = blockIdx.x; i < cnt_rows; i += gridDim.x) {
        const size_t r = list[i];
        xsh[tid] = x[r * 256 + tid];
        __syncthreads();

        double acc = 0.0;
        const float4* wr4 = (const float4*)(W + (size_t)tid * 256);
        #pragma unroll 4
        for (int d4 = 0; d4 < 64; ++d4) {
            float4 w = wr4[d4];
            float4 xx = *(const float4*)&xsh[d4 * 4];
            acc = fma((double)w.x, (double)xx.x, acc);
            acc = fma((double)w.y, (double)xx.y, acc);
            acc = fma((double)w.z, (double)xx.z, acc);
            acc = fma((double)w.w, (double)xx.w, acc);
        }
        zsh[tid] = acc;
        __syncthreads();

        if (tid < 64) {
            double zd[4];
            #pragma unroll
            for (int q = 0; q < 4; ++q) zd[q] = zsh[tid * 4 + q];
            double S = ((zd[0] + zd[1]) + (zd[2] + zd[3]));
            #pragma unroll
            for (int m = 1; m < 64; m <<= 1) S += __shfl_xor(S, m, 64);
            CE2(0, 1) CE2(2, 3) CE2(0, 2) CE2(1, 3) CE2(1, 2)

            double R = S, Rp = 0.0, mlast = 0.0;
            int ii = 0;
            #pragma unroll 1
            while (R <= 1.0 && ii < 64) {
                double m = zd[0];
                #pragma unroll
                for (int mm = 1; mm < 64; mm <<= 1) m = fmin(m, __shfl_xor(m, mm, 64));
                unsigned long long bal = __ballot(zd[0] == m);
                int below = __builtin_amdgcn_mbcnt_hi(
                    (unsigned int)(bal >> 32),
                    __builtin_amdgcn_mbcnt_lo((unsigned int)bal, 0));
                const bool first = (zd[0] == m) && (below == 0);
                zd[0] = first ? zd[1] : zd[0];
                zd[1] = first ? zd[2] : zd[1];
                zd[2] = first ? zd[3] : zd[2];
                zd[3] = first ? 1.0e300 : zd[3];
                Rp = R; mlast = m;
                R = R - m;
                ++ii;
            }

            double b1 = zd[0];
            #pragma unroll
            for (int mm = 1; mm < 64; mm <<= 1) b1 = fmin(b1, __shfl_xor(b1, mm, 64));
            {
                unsigned long long bal = __ballot(zd[0] == b1);
                int below = __builtin_amdgcn_mbcnt_hi(
                    (unsigned int)(bal >> 32),
                    __builtin_amdgcn_mbcnt_lo((unsigned int)bal, 0));
                const bool first = (zd[0] == b1) && (below == 0);
                zd[0] = first ? zd[1] : zd[0];
                zd[1] = first ? zd[2] : zd[1];
                zd[2] = first ? zd[3] : zd[2];
                zd[3] = first ? 1.0e300 : zd[3];
            }
            double b2 = zd[0];
            #pragma unroll
            for (int mm = 1; mm < 64; mm <<= 1) b2 = fmin(b2, __shfl_xor(b2, mm, 64));

            const int K = 256 - ii;
            const double Kd = (double)K;
            const double tau_m = ((1.0 + Kd * b1) - R) / Kd;
            double tau_p = tau_m, tau_q = tau_m;
            if (ii >= 1)
                tau_p = ((1.0 + (Kd + 1.0) * mlast) - Rp) / (Kd + 1.0);
            if (K >= 2)
                tau_q = ((1.0 + (Kd - 1.0) * b2) - (R - b1)) / (Kd - 1.0);
            double mg = fabs(R - 1.0);
            if (ii >= 1) mg = fmin(mg, fabs(Rp - 1.0));

            if (tid == 0) {
                par[0] = tau_m; par[1] = tau_p; par[2] = tau_q;
                par[3] = mg;    par[4] = (double)K;
            }
        }
        __syncthreads();

        const double tau_m = par[0], tau_p = par[1], tau_q = par[2];
        const int K = (int)par[4];
        const bool hasp = (K <= 255);
        const bool hasq = (K >= 2);

        const float om = bf16f((float)fmax(zsh[tid] - tau_m, 0.0));
        const float op = bf16f((float)fmax(zsh[tid] - tau_p, 0.0));
        const float oq = bf16f((float)fmax(zsh[tid] - tau_q, 0.0));
        float dp = fabsf(op - om);
        float dq = fabsf(oq - om);
        #pragma unroll
        for (int m = 1; m < 64; m <<= 1) {
            dp = fmaxf(dp, __shfl_xor(dp, m, 64));
            dq = fmaxf(dq, __shfl_xor(dq, m, 64));
        }
        if ((tid & 63) == 0) { red[tid >> 6][0] = dp; red[tid >> 6][1] = dq; }
        __syncthreads();

        if (tid == 0) {
            const float Ep = fmaxf(fmaxf(red[0][0], red[1][0]),
                                   fmaxf(red[2][0], red[3][0]));
            const float Eq = fmaxf(fmaxf(red[0][1], red[1][1]),
                                   fmaxf(red[2][1], red[3][1]));
            double tf = tau_m;
            if (par[3] < 1.2e-4) {
                const float EL[1] = {0.46875f};
                #pragma unroll
                for (int t = 0; t < 1; ++t) {
                    if (hasp && Ep == EL[t]) { tf = tau_p; break; }
                    if (hasq && Eq == EL[t]) { tf = tau_q; break; }
                }
            }
            par[5] = tf;
        }
        __syncthreads();

        out[r * 256 + tid] = (float)fmax(zsh[tid] - par[5], 0.0);
        __syncthreads();
    }
}

extern "C" void kernel_launch(void* const* d_in, const int* in_sizes, int n_in,
                              void* d_out, int out_size, void* d_ws, size_t ws_size,
                              hipStream_t stream) {
    const float* x = (const float*)d_in[0];
    const float* W = (const float*)d_in[1];
    float* out = (float*)d_out;

    unsigned short* Wp = (unsigned short*)d_ws;
    unsigned int* counter = (unsigned int*)((char*)d_ws + 262144);
    unsigned int* list    = (unsigned int*)((char*)d_ws + 262144 + 64);

    hipLaunchKernelGGL(prep_kernel, dim3(256), dim3(256), 0, stream, W, Wp, counter);

    const int N = in_sizes[0] / 256;   // 262144
    hipLaunchKernelGGL(pass1_fused, dim3(N / 64), dim3(256), 0, stream,
                       x, Wp, out, counter, list);
    hipLaunchKernelGGL(exact_redo_f64, dim3(8192), dim3(256), 0, stream,
                       x, W, counter, list, out);
}